// Round 9
// baseline (264.363 us; speedup 1.0000x reference)
//
#include <hip/hip_runtime.h>
#include <cstdint>
#include <cstddef>

// Match numpy/XLA float32 semantics: no FMA contraction anywhere.
#pragma clang fp contract(off)

#define KCLS 9
#define PRE_N 6000
#define POST_N 300
#define NMS_IOU_T 0.7f
#define HIST_BLOCK 256
#define CHUNKS_PER_IMG 32
#define NMS_BLOCK 512
#define PICK_BLOCK 256
#define NSEG 8
#define SEG_CAP 2048
#define RANK_LDS 8192   // rank_decode fast-path capacity (total candidates ~6000+eps)

// Decisive-margin suppression test: multiply prescreen with +-1e-6 margins,
// exact reference division only in the borderline window -> bit-identical
// decisions to `inter/den > 0.7f` with reference float op order.
#define SUPP(pb, pa, mbx, mar, out) \
    bool out; { \
        float iy1_ = fmaxf((pb).x, (mbx).x); \
        float ix1_ = fmaxf((pb).y, (mbx).y); \
        float iy2_ = fminf((pb).z, (mbx).z); \
        float ix2_ = fminf((pb).w, (mbx).w); \
        float ih_ = iy2_ - iy1_; ih_ = ih_ > 0.f ? ih_ : 0.f; \
        float iw_ = ix2_ - ix1_; iw_ = iw_ > 0.f ? iw_ : 0.f; \
        float inter_ = ih_ * iw_; \
        float den_ = (mar) + (pa) - inter_ + 1e-9f; \
        float hi_ = 0.7000007f * den_; \
        float lo_ = 0.6999993f * den_; \
        out = inter_ > hi_; \
        if (inter_ >= lo_ && inter_ <= hi_) out = (inter_ / den_) > NMS_IOU_T; \
    }

// ---------------- stage 1: softmax over K=9 (LDS-staged coalesced IO) + pass-1 hist ----------------
__global__ void __launch_bounds__(256)
softmax_hist_kernel(const float* __restrict__ labels,
                    float* __restrict__ scores,
                    unsigned int* __restrict__ ghist,   // [B][2048] (pass-1 slot)
                    int gpi) {                          // groups per image (16384)
    __shared__ float buf[256 * KCLS];                   // 9216 B
    __shared__ unsigned int h[2048];                    // 8192 B
    const int tid = threadIdx.x;
    for (int i = tid; i < 2048; i += 256) h[i] = 0u;

    const size_t gbase = (size_t)blockIdx.x * (256 * KCLS);
    const float4* lin4 = (const float4*)(labels + gbase);
    float4* b4 = (float4*)buf;
    for (int i = tid; i < 576; i += 256) b4[i] = lin4[i];   // coalesced 16B loads
    __syncthreads();

    // per-thread softmax on buf[tid*9 .. +8]; stride-9 LDS = 2-way aliasing (free)
    float v[KCLS];
    float m = -1e30f;
    #pragma unroll
    for (int k = 0; k < KCLS; ++k) { v[k] = buf[tid * KCLS + k]; m = fmaxf(m, v[k]); }
    float e[KCLS];
    float s = 0.f;
    #pragma unroll
    for (int k = 0; k < KCLS; ++k) { e[k] = expf(v[k] - m); s += e[k]; }
    #pragma unroll
    for (int k = 0; k < KCLS; ++k) {
        float r = e[k] / s;
        buf[tid * KCLS + k] = r;                        // own slots only: no hazard
        atomicAdd(&h[(__float_as_uint(r) >> 21) & 2047u], 1u);
    }
    __syncthreads();

    float4* o4 = (float4*)(scores + gbase);
    for (int i = tid; i < 576; i += 256) o4[i] = b4[i];     // coalesced 16B stores

    const int img0 = (blockIdx.x * 256) / gpi;          // block spans one image
    unsigned int* gh = ghist + (size_t)img0 * 2048;
    for (int i = tid; i < 2048; i += 256) {
        unsigned int c = h[i];
        if (c) atomicAdd(&gh[i], c);
    }
}

// ---------------- stage 2a: radix histogram pass 2 ----------------
__global__ void hist_kernel(const float* __restrict__ scores,
                            unsigned int* __restrict__ ghist,        // [B][2048]
                            const unsigned int* __restrict__ state,  // [B][2] {prefix,krem}
                            int A, int shift, int bins, unsigned int pmask) {
    __shared__ unsigned int h[2048];
    const int img = blockIdx.y;
    const int chunk = blockIdx.x;
    const int tid = threadIdx.x;
    for (int i = tid; i < bins; i += HIST_BLOCK) h[i] = 0u;
    __syncthreads();
    unsigned int prefix = state[img * 2 + 0] & pmask;
    const int per = A / CHUNKS_PER_IMG;
    const float* sc = scores + (size_t)img * A + (size_t)chunk * per;
    for (int i = tid; i < per; i += HIST_BLOCK) {
        unsigned int v = __float_as_uint(sc[i]);   // scores > 0: uint order == float order
        if ((v & pmask) == prefix)
            atomicAdd(&h[(v >> shift) & (unsigned)(bins - 1)], 1u);
    }
    __syncthreads();
    unsigned int* gh = ghist + (size_t)img * 2048;
    for (int i = tid; i < bins; i += HIST_BLOCK) {
        unsigned int c = h[i];
        if (c) atomicAdd(&gh[i], c);
    }
}

// ---------------- stage 2b: pick target bin (parallel suffix scan) ----------------
__global__ void __launch_bounds__(PICK_BLOCK)
pick_kernel(const unsigned int* __restrict__ ghist,
            unsigned int* __restrict__ state,
            int shift, int bins, int first_pass) {
    const int img = blockIdx.x;
    const int t = threadIdx.x;
    const unsigned int* gh = ghist + (size_t)img * 2048;
    __shared__ unsigned int cnt[2048];
    __shared__ unsigned int ssum[PICK_BLOCK];
    const int per = bins / PICK_BLOCK;   // 8
    unsigned int my = 0;
    for (int i = 0; i < per; ++i) {
        unsigned int c = gh[t * per + i];
        cnt[t * per + i] = c;
        my += c;
    }
    ssum[t] = my;
    __syncthreads();
    // inclusive suffix scan: ssum[t] = sum_{u >= t} chunk_sum[u]
    for (int d = 1; d < PICK_BLOCK; d <<= 1) {
        unsigned int v = (t + d < PICK_BLOCK) ? ssum[t + d] : 0u;
        __syncthreads();
        ssum[t] += v;
        __syncthreads();
    }
    unsigned int prefix = first_pass ? 0u : state[img * 2 + 0];
    unsigned int krem = first_pass ? (unsigned)PRE_N : state[img * 2 + 1];
    unsigned int above = ssum[t] - my;   // strictly above my chunk
    if (above < krem && ssum[t] >= krem) {   // unique thread
        unsigned int cum = above;
        for (int b = per - 1; b >= 0; --b) {
            unsigned int c = cnt[t * per + b];
            if (cum + c >= krem) {
                state[img * 2 + 0] = prefix | ((unsigned int)(t * per + b) << shift);
                state[img * 2 + 1] = krem - cum;
                break;
            }
            cum += c;
        }
    }
}

// ---------------- stage 2c: per-segment compact + register-blocked bitonic sort ----------------
// T = state[0] after TWO radix passes = top-22 bits of the 6000th-largest score
// (low 10 bits zero). Loose-but-safe threshold; exact top-6000 cut happens on
// full 64-bit keys in rank_decode -> output identical.
#define CE(a, b, u) { if ((v[a] > v[b]) == (u)) { unsigned long long t_ = v[a]; v[a] = v[b]; v[b] = t_; } }
#define REG3(u) { CE(0,4,u) CE(1,5,u) CE(2,6,u) CE(3,7,u) \
                  CE(0,2,u) CE(1,3,u) CE(4,6,u) CE(5,7,u) \
                  CE(0,1,u) CE(2,3,u) CE(4,5,u) CE(6,7,u) }

__global__ void __launch_bounds__(512)
compact_sort_kernel(const float* __restrict__ scores,
                    const unsigned int* __restrict__ state,
                    unsigned long long* __restrict__ pool,   // [B][NSEG][SEG_CAP]
                    unsigned int* __restrict__ counts,       // [B][NSEG]
                    int A) {
    __shared__ unsigned long long lin[SEG_CAP];   // 16 KB
    __shared__ unsigned int plo[2][SEG_CAP];      // 16 KB
    __shared__ unsigned int phi[2][SEG_CAP];      // 16 KB
    __shared__ unsigned int cnt;
    const int img = blockIdx.y;
    const int seg = blockIdx.x;
    const int tid = threadIdx.x;
    const int lane = tid & 63;
    const int w = tid >> 6;                       // wave 0..7
    const float* sc = scores + (size_t)img * A;
    const unsigned int T = state[img * 2 + 0];    // 22-bit-prefix threshold

    if (tid == 0) cnt = 0u;
    for (int i = tid; i < SEG_CAP; i += 512) lin[i] = ~0ull;  // pad keys = max
    __syncthreads();

    // compact: groups g == seg (mod NSEG), wave-aggregated LDS push
    const int ngr = A >> 6;                       // 64-element groups (2304)
    const int nj = ngr / NSEG;                    // groups per segment (288)
    for (int j = w; j < nj; j += 8) {             // 36 iterations per wave
        int g = seg + j * NSEG;
        int i = (g << 6) + lane;
        unsigned int sv = __float_as_uint(sc[i]); // scores > 0: uint order == float order
        bool push = (sv >= T);
        unsigned long long bal = __ballot(push ? 1 : 0);
        if (push) {
            int leader = __ffsll(bal) - 1;
            int rank = __popcll(bal & ((1ull << lane) - 1ull));
            unsigned int base = 0;
            if (lane == leader) base = atomicAdd(&cnt, (unsigned int)__popcll(bal));
            base = (unsigned int)__shfl((int)base, leader);
            unsigned int pos = base + (unsigned int)rank;
            if (pos < SEG_CAP)
                lin[pos] = (((unsigned long long)(~sv)) << 32) | (unsigned long long)(unsigned int)i;
        }
    }
    __syncthreads();

    int n = (int)cnt; if (n > SEG_CAP) n = SEG_CAP;
    int P2 = 512; while (P2 < n) P2 <<= 1;        // 512..2048 (block-uniform)
    const int NT = P2 >> 3;                       // active threads
    const int t = tid;
    const bool act = (t < NT);

    unsigned long long v[8];
    if (act) {
        #pragma unroll
        for (int e = 0; e < 8; ++e) v[e] = lin[(t << 3) + e];
        // k=2,4,8 (in-register)
        CE(0,1,true) CE(2,3,false) CE(4,5,true) CE(6,7,false)
        CE(0,2,true) CE(1,3,true) CE(4,6,false) CE(5,7,false)
        CE(0,1,true) CE(2,3,true) CE(4,5,false) CE(6,7,false)
        bool u8 = ((t & 1) == 0);
        REG3(u8)
    }
    int b = 0;
    for (int k = 16; k <= P2; k <<= 1) {
        const bool up = (((t << 3) & k) == 0);
        for (int j = k >> 1; j >= 8; j >>= 1) {
            const int c = j >> 3;
            if (act) {
                #pragma unroll
                for (int e = 0; e < 8; ++e) {
                    int idx = e * NT + t;
                    plo[b][idx] = (unsigned int)v[e];
                    phi[b][idx] = (unsigned int)(v[e] >> 32);
                }
            }
            __syncthreads();
            if (act) {
                const int q = t ^ c;
                const bool keep_min = (up == ((t & c) == 0));
                #pragma unroll
                for (int e = 0; e < 8; ++e) {
                    int idx = e * NT + q;
                    unsigned long long wv = ((unsigned long long)phi[b][idx] << 32)
                                          | (unsigned long long)plo[b][idx];
                    bool less = v[e] < wv;
                    v[e] = (less == keep_min) ? v[e] : wv;
                }
            }
            b ^= 1;
        }
        if (act) { REG3(up) }
    }

    unsigned long long* gp = pool + ((size_t)img * NSEG + seg) * SEG_CAP;
    if (act) {
        #pragma unroll
        for (int e = 0; e < 8; ++e) {
            int r = (t << 3) + e;
            if (r < n) gp[r] = v[e];
        }
    }
    if (tid == 0) counts[img * NSEG + seg] = (unsigned int)n;
}

// ---------------- stage 2d: rank (merge by binary search) + decode ----------------
__global__ void __launch_bounds__(256)
rank_decode_kernel(const unsigned long long* __restrict__ pool,
                   const unsigned int* __restrict__ counts,
                   const float* __restrict__ deltas,   // [B][A][4]
                   const float* __restrict__ anchors,  // [A][4]
                   float* __restrict__ pre_boxes,      // [B][6000][4]
                   float* __restrict__ pre_scores,     // [B][6000]
                   int A) {
    __shared__ unsigned long long arr[RANK_LDS];   // 64 KB (total ~6000 -> fast path)
    const int img = blockIdx.y;
    const int seg = blockIdx.x;
    const int tid = threadIdx.x;

    int c[NSEG], off[NSEG + 1];
    const unsigned long long* gp[NSEG];
    off[0] = 0;
    #pragma unroll
    for (int s = 0; s < NSEG; ++s) {
        int cs = (int)counts[img * NSEG + s];
        if (cs > SEG_CAP) cs = SEG_CAP;
        c[s] = cs;
        off[s + 1] = off[s] + cs;
        gp[s] = pool + ((size_t)img * NSEG + s) * SEG_CAP;
    }
    const int total = off[NSEG];
    const bool inlds = (total <= RANK_LDS);
    if (inlds) {
        #pragma unroll
        for (int s = 0; s < NSEG; ++s)
            for (int i = tid; i < c[s]; i += 256) arr[off[s] + i] = gp[s][i];
    }
    __syncthreads();

    const int m = c[seg];
    for (int i = tid; i < m; i += 256) {
        unsigned long long key = inlds ? arr[off[seg] + i] : gp[seg][i];
        int pos = i;
        #pragma unroll
        for (int s = 0; s < NSEG; ++s) {
            if (s == seg) continue;
            const unsigned long long* base = inlds ? (arr + off[s]) : gp[s];
            int lo = 0, hi = c[s];
            while (lo < hi) {
                int mid = (lo + hi) >> 1;
                if (base[mid] < key) lo = mid + 1; else hi = mid;
            }
            pos += lo;
        }
        if (pos < PRE_N) {
            unsigned int bidx = (unsigned int)(key & 0xFFFFFFFFull);
            unsigned int sbits = ~((unsigned int)(key >> 32));
            float score = __uint_as_float(sbits);
            float a0 = anchors[(size_t)bidx * 4 + 0];
            float a1 = anchors[(size_t)bidx * 4 + 1];
            float a2 = anchors[(size_t)bidx * 4 + 2];
            float a3 = anchors[(size_t)bidx * 4 + 3];
            const float* dd = deltas + ((size_t)img * A + bidx) * 4;
            float d0 = dd[0] * 0.1f;
            float d1 = dd[1] * 0.1f;
            float d2 = dd[2] * 0.2f;
            float d3 = dd[3] * 0.2f;
            float anc_w = a3 - a1;
            float anc_h = a2 - a0;
            float anc_cx = a1 + 0.5f * anc_w;
            float anc_cy = a0 + 0.5f * anc_h;
            float bb_w = expf(d3) * anc_w;
            float bb_h = expf(d2) * anc_h;
            float bb_cx = d1 * anc_w + anc_cx;
            float bb_cy = d0 * anc_h + anc_cy;
            float y1 = bb_cy - 0.5f * bb_h;
            float x1 = bb_cx - 0.5f * bb_w;
            float y2 = bb_h + y1;
            float x2 = bb_w + x1;
            float* ob = pre_boxes + ((size_t)img * PRE_N + pos) * 4;
            ob[0] = y1; ob[1] = x1; ob[2] = y2; ob[3] = x2;
            pre_scores[(size_t)img * PRE_N + pos] = score;
        }
    }
}

// ---------------- stage 3: chunked greedy NMS (prefetched E + row-ballot + ffs) ----------------
// Round-8 structure with ONE change: phase E software-prefetches kept[k+8]
// (clamped index) before the break-dependent SUPP, so the ~150-cycle LDS load
// latency overlaps the test instead of serializing behind the branch. Counters
// showed E exits after ~4-5 iterations (top-score kept boxes suppress almost
// everything) -> the dependent load->test->branch chain was the dominant cost.
__global__ void __launch_bounds__(NMS_BLOCK)
nms_kernel(const float* __restrict__ pre_boxes,
           const float* __restrict__ pre_scores,
           float* __restrict__ out_boxes,    // [B][300][4] (pre-zeroed)
           float* __restrict__ out_scores) { // [B][300]
    const int img = blockIdx.x;
    const int tid = threadIdx.x;
    const int lane = tid & 63;
    const int grp = tid >> 6;                 // 0..7
    const float4* bb4 = (const float4*)(pre_boxes + (size_t)img * PRE_N * 4);

    __shared__ float4 kept[POST_N];
    __shared__ float  kept_area[POST_N];
    __shared__ int    kept_idx[POST_N];
    __shared__ float4 chunkbox[2][64];              // double buffer
    __shared__ unsigned long long rows[64];         // row i: boxes suppressed by pivot i
    __shared__ unsigned long long supball[8];       // phase-E per-wave suppressed sets
    __shared__ int kept_cnt;

    const int NCH = (PRE_N + 63) >> 6;        // 94 (last chunk: 48 valid)

    // prologue: stage chunk 0, prefetch chunk 1, init
    float4 nb = make_float4(0.f, 0.f, 0.f, 0.f);
    if (tid < 64) {
        chunkbox[0][tid] = bb4[tid];
        nb = bb4[64 + tid];                   // chunk 1 fully valid (128 <= 6000)
    }
    if (tid == 0) kept_cnt = 0;
    __syncthreads();

    for (int c = 0; c < NCH; ++c) {
        const int base = c << 6;
        const int cur = c & 1;
        const int K = kept_cnt;
        float4 mb = chunkbox[cur][lane];
        float marea = (mb.z - mb.x) * (mb.w - mb.y);

        // ---- phase E: external suppression, prefetched across the break ----
        bool sup = false;
        {
            int k = grp;
            if (k < K) {
                float4 pb = kept[k];
                float pa = kept_area[k];
                for (;;) {
                    const int k2 = k + 8;
                    const int kp = (k2 < K) ? k2 : k;   // clamped (in-bounds) prefetch
                    float4 pb2 = kept[kp];              // issues before the branch
                    float pa2 = kept_area[kp];
                    SUPP(pb, pa, mb, marea, s)
                    if (s) { sup = true; break; }
                    if (k2 >= K) break;
                    k = k2; pb = pb2; pa = pa2;
                }
            }
        }
        unsigned long long bal = __ballot(sup ? 1 : 0);
        if (lane == 0) supball[grp] = bal;    // always write (0 when none)

        // ---- phase M: row masks (8 pivots per wave vs all 64 boxes) ----
        #pragma unroll
        for (int u = 0; u < 8; ++u) {
            const int i = (grp << 3) + u;
            float4 pb = chunkbox[cur][i];     // uniform per iteration -> broadcast
            float pa = (pb.z - pb.x) * (pb.w - pb.y);
            SUPP(pb, pa, mb, marea, s)
            unsigned long long rb = __ballot(s ? 1 : 0);
            if (lane == 0) rows[i] = rb;
        }

        // ---- staging: publish chunk c+1, prefetch chunk c+2 ----
        if (tid < 64) {
            chunkbox[cur ^ 1][tid] = nb;
            int j = base + 128 + tid;
            nb = (j < PRE_N) ? bb4[j] : make_float4(0.f, 0.f, 0.f, 0.f);
        }
        __syncthreads();                      // (B) supball + rows + staging visible

        // ---- phase R: wave-0 ffs-ordered resolution over alive boxes only ----
        if (grp == 0) {
            const int remn = PRE_N - base;
            unsigned long long ext = (remn >= 64) ? ~0ull : ((1ull << remn) - 1ull);
            unsigned long long sb = supball[0] | supball[1] | supball[2] | supball[3]
                                  | supball[4] | supball[5] | supball[6] | supball[7];
            unsigned long long rem = ext & ~sb;
            unsigned long long myrow = rows[lane];   // row for pivot 'lane'
            int kc = K;
            while (rem && kc < POST_N) {
                const int i = __ffsll(rem) - 1;      // lowest alive = highest score
                if (lane == i) {                     // lane i holds box i in registers
                    kept[kc] = mb;
                    kept_area[kc] = marea;
                    kept_idx[kc] = base + i;
                }
                unsigned long long ri = __shfl(myrow, i);
                rem &= ~(1ull << i);
                rem &= ~ri;                          // row's j<i bits unreachable (ffs)
                ++kc;
            }
            if (lane == 0) kept_cnt = kc;
        }
        __syncthreads();                      // (C) kept list + count visible
        if (kept_cnt >= POST_N) break;        // uniform
    }

    // ---- write outputs (rest of the pre-zeroed buffer stays zero) ----
    const int kc = kept_cnt;
    for (int r = tid; r < kc; r += NMS_BLOCK) {
        float4 bx = kept[r];
        float* ob = out_boxes + ((size_t)img * POST_N + r) * 4;
        ob[0] = bx.x; ob[1] = bx.y; ob[2] = bx.z; ob[3] = bx.w;
        out_scores[(size_t)img * POST_N + r] =
            pre_scores[(size_t)img * PRE_N + kept_idx[r]];
    }
}

extern "C" void kernel_launch(void* const* d_in, const int* in_sizes, int n_in,
                              void* d_out, int out_size, void* d_ws, size_t ws_size,
                              hipStream_t stream) {
    const float* deltas  = (const float*)d_in[0];  // (B, A, 4)
    const float* labels  = (const float*)d_in[1];  // (B, FH, FW, 9)
    const float* anchors = (const float*)d_in[2];  // (A, 4)
    float* out = (float*)d_out;

    const int A = in_sizes[2] / 4;                 // 147456
    const int B = in_sizes[0] / (A * 4);           // 32
    const int ngroups = in_sizes[1] / KCLS;        // B*FH*FW
    const int gpi = ngroups / B;                   // 16384

    // workspace layout
    float* scores     = (float*)d_ws;                                // B*A
    float* pre_boxes  = scores + (size_t)B * A;                      // B*6000*4
    float* pre_scores = pre_boxes + (size_t)B * PRE_N * 4;           // B*6000
    unsigned int* hist  = (unsigned int*)(pre_scores + (size_t)B * PRE_N);  // 2*B*2048
    unsigned int* state = hist + (size_t)2 * B * 2048;               // B*2
    unsigned long long* pool = (unsigned long long*)(state + (size_t)B * 2); // B*NSEG*SEG_CAP u64
    unsigned int* counts = (unsigned int*)(pool + (size_t)B * NSEG * SEG_CAP); // B*NSEG

    float* out_boxes  = out;                        // B*300*4
    float* out_scores = out + (size_t)B * POST_N * 4;

    hipMemsetAsync(d_out, 0, (size_t)out_size * sizeof(float), stream);
    hipMemsetAsync(hist, 0, ((size_t)2 * B * 2048 + 2 * B) * sizeof(unsigned int), stream);

    // pass 1 (bits [31:21]) fused into softmax
    softmax_hist_kernel<<<ngroups / 256, 256, 0, stream>>>(
        labels, scores, hist + (size_t)0 * B * 2048, gpi);
    pick_kernel<<<B, PICK_BLOCK, 0, stream>>>(hist + (size_t)0 * B * 2048, state, 21, 2048, 1);

    dim3 hgrid(CHUNKS_PER_IMG, B);
    // pass 2: bits [20:10] -> T = exact top-22-bit prefix of the 6000th score
    hist_kernel<<<hgrid, HIST_BLOCK, 0, stream>>>(
        scores, hist + (size_t)1 * B * 2048, state, A, 10, 2048, 0xFFE00000u);
    pick_kernel<<<B, PICK_BLOCK, 0, stream>>>(hist + (size_t)1 * B * 2048, state, 10, 2048, 0);

    dim3 sgrid(NSEG, B);
    compact_sort_kernel<<<sgrid, 512, 0, stream>>>(scores, state, pool, counts, A);
    rank_decode_kernel<<<sgrid, 256, 0, stream>>>(pool, counts, deltas, anchors,
                                                  pre_boxes, pre_scores, A);

    nms_kernel<<<B, NMS_BLOCK, 0, stream>>>(pre_boxes, pre_scores, out_boxes, out_scores);
}

// Round 10
// 262.939 us; speedup vs baseline: 1.0054x; 1.0054x over previous
//
#include <hip/hip_runtime.h>
#include <cstdint>
#include <cstddef>

// Match numpy/XLA float32 semantics: no FMA contraction anywhere.
#pragma clang fp contract(off)

#define KCLS 9
#define PRE_N 6000
#define POST_N 300
#define NMS_IOU_T 0.7f
#define HIST_BLOCK 256
#define CHUNKS_PER_IMG 32
#define NMS_BLOCK 512
#define NSEG 8
#define SEG_CAP 2048
#define RANK_LDS 8192   // rank_decode fast-path capacity (total candidates ~6000+eps)

// Decisive-margin suppression test: multiply prescreen with +-1e-6 margins,
// exact reference division only in the borderline window -> bit-identical
// decisions to `inter/den > 0.7f` with reference float op order.
#define SUPP(pb, pa, mbx, mar, out) \
    bool out; { \
        float iy1_ = fmaxf((pb).x, (mbx).x); \
        float ix1_ = fmaxf((pb).y, (mbx).y); \
        float iy2_ = fminf((pb).z, (mbx).z); \
        float ix2_ = fminf((pb).w, (mbx).w); \
        float ih_ = iy2_ - iy1_; ih_ = ih_ > 0.f ? ih_ : 0.f; \
        float iw_ = ix2_ - ix1_; iw_ = iw_ > 0.f ? iw_ : 0.f; \
        float inter_ = ih_ * iw_; \
        float den_ = (mar) + (pa) - inter_ + 1e-9f; \
        float hi_ = 0.7000007f * den_; \
        float lo_ = 0.6999993f * den_; \
        out = inter_ > hi_; \
        if (inter_ >= lo_ && inter_ <= hi_) out = (inter_ / den_) > NMS_IOU_T; \
    }

// ---- in-block pick: suffix-scan a 2048-bin global histogram (L2-resident) ----
// Run redundantly by every consumer block; replaces the standalone pick_kernel
// dispatches. Identical math to the old pick_kernel. Threads >=256 idle through
// the (block-wide) barriers. Result left in out[0]=prefix, out[1]=krem.
__device__ __forceinline__ void pick_dev(
        const unsigned int* __restrict__ gh,   // [bins] global histogram
        int shift, int bins,
        unsigned int prefix_in, unsigned int krem_in,
        unsigned int* cnt,      // LDS >= bins
        unsigned int* ssum,     // LDS 256
        unsigned int* out) {    // LDS 2
    const int t = threadIdx.x;
    const int per = bins >> 8;
    unsigned int my = 0;
    if (t < 256) {
        for (int i = 0; i < per; ++i) {
            unsigned int c = gh[t * per + i];
            cnt[t * per + i] = c;
            my += c;
        }
        ssum[t] = my;
    }
    __syncthreads();
    // inclusive suffix scan over the 256 chunk sums
    for (int d = 1; d < 256; d <<= 1) {
        unsigned int v = 0u;
        if (t < 256 && t + d < 256) v = ssum[t + d];
        __syncthreads();
        if (t < 256) ssum[t] += v;
        __syncthreads();
    }
    if (t < 256) {
        unsigned int above = ssum[t] - my;        // strictly above my chunk
        if (above < krem_in && ssum[t] >= krem_in) {   // unique thread
            unsigned int cum = above;
            for (int b = per - 1; b >= 0; --b) {
                unsigned int c = cnt[t * per + b];
                if (cum + c >= krem_in) {
                    out[0] = prefix_in | ((unsigned int)(t * per + b) << shift);
                    out[1] = krem_in - cum;
                    break;
                }
                cum += c;
            }
        }
    }
    __syncthreads();
}

// ---------------- stage 1: softmax over K=9 (coalesced IO) + pass-1 hist (sub x4) ----------------
__global__ void __launch_bounds__(256)
softmax_hist_kernel(const float* __restrict__ labels,
                    float* __restrict__ scores,
                    unsigned int* __restrict__ ghist,   // [B][2048] (pass-1 slot)
                    int gpi) {                          // groups per image (16384)
    __shared__ float buf[256 * KCLS];                   // 9216 B
    __shared__ unsigned int h[2048 * 4];                // 32 KB, 4 sub-histograms
    const int tid = threadIdx.x;
    for (int i = tid; i < 2048 * 4; i += 256) h[i] = 0u;

    const size_t gbase = (size_t)blockIdx.x * (256 * KCLS);
    const float4* lin4 = (const float4*)(labels + gbase);
    float4* b4 = (float4*)buf;
    for (int i = tid; i < 576; i += 256) b4[i] = lin4[i];   // coalesced 16B loads
    __syncthreads();

    // per-thread softmax on buf[tid*9 .. +8]; stride-9 LDS = 2-way aliasing (free)
    const int sub = tid & 3;                            // 4-way same-address spread
    float v[KCLS];
    float m = -1e30f;
    #pragma unroll
    for (int k = 0; k < KCLS; ++k) { v[k] = buf[tid * KCLS + k]; m = fmaxf(m, v[k]); }
    float e[KCLS];
    float s = 0.f;
    #pragma unroll
    for (int k = 0; k < KCLS; ++k) { e[k] = expf(v[k] - m); s += e[k]; }
    #pragma unroll
    for (int k = 0; k < KCLS; ++k) {
        float r = e[k] / s;
        buf[tid * KCLS + k] = r;                        // own slots only: no hazard
        atomicAdd(&h[(((__float_as_uint(r) >> 21) & 2047u) << 2) | sub], 1u);
    }
    __syncthreads();

    float4* o4 = (float4*)(scores + gbase);
    for (int i = tid; i < 576; i += 256) o4[i] = b4[i];     // coalesced 16B stores

    const int img0 = (blockIdx.x * 256) / gpi;          // block spans one image
    unsigned int* gh = ghist + (size_t)img0 * 2048;
    for (int i = tid; i < 2048; i += 256) {
        unsigned int c = h[4 * i] + h[4 * i + 1] + h[4 * i + 2] + h[4 * i + 3];
        if (c) atomicAdd(&gh[i], c);
    }
}

// ---------------- stage 2a: radix pass 2 (in-block pick1 + histogram) ----------------
__global__ void __launch_bounds__(HIST_BLOCK)
hist2_kernel(const float* __restrict__ scores,
             const unsigned int* __restrict__ ghist1,   // [B][2048] pass-1
             unsigned int* __restrict__ ghist2,         // [B][2048] pass-2
             int A) {
    __shared__ unsigned int h[2048];
    __shared__ unsigned int ssum[256];
    __shared__ unsigned int pk[2];
    const int img = blockIdx.y;
    const int chunk = blockIdx.x;
    const int tid = threadIdx.x;

    // redundant pick1: bins [31:21], krem = 6000
    pick_dev(ghist1 + (size_t)img * 2048, 21, 2048, 0u, (unsigned)PRE_N, h, ssum, pk);
    const unsigned int prefix = pk[0];                  // low 21 bits zero

    for (int i = tid; i < 2048; i += HIST_BLOCK) h[i] = 0u;
    __syncthreads();
    const int per = A / CHUNKS_PER_IMG;
    const float* sc = scores + (size_t)img * A + (size_t)chunk * per;
    for (int i = tid; i < per; i += HIST_BLOCK) {
        unsigned int v = __float_as_uint(sc[i]);   // scores > 0: uint order == float order
        if ((v & 0xFFE00000u) == prefix)
            atomicAdd(&h[(v >> 10) & 2047u], 1u);
    }
    __syncthreads();
    unsigned int* gh = ghist2 + (size_t)img * 2048;
    for (int i = tid; i < 2048; i += HIST_BLOCK) {
        unsigned int c = h[i];
        if (c) atomicAdd(&gh[i], c);
    }
}

// ---------------- stage 2c: per-segment compact + register-blocked bitonic sort ----------------
// In-block pick1+pick2 -> T = top-22-bit prefix of the 6000th-largest score
// (low 10 bits zero). Loose-but-safe threshold; exact top-6000 cut happens on
// full 64-bit keys in rank_decode -> output identical.
#define CE(a, b, u) { if ((v[a] > v[b]) == (u)) { unsigned long long t_ = v[a]; v[a] = v[b]; v[b] = t_; } }
#define REG3(u) { CE(0,4,u) CE(1,5,u) CE(2,6,u) CE(3,7,u) \
                  CE(0,2,u) CE(1,3,u) CE(4,6,u) CE(5,7,u) \
                  CE(0,1,u) CE(2,3,u) CE(4,5,u) CE(6,7,u) }

__global__ void __launch_bounds__(512)
compact_sort_kernel(const float* __restrict__ scores,
                    const unsigned int* __restrict__ ghist1,
                    const unsigned int* __restrict__ ghist2,
                    unsigned long long* __restrict__ pool,   // [B][NSEG][SEG_CAP]
                    unsigned int* __restrict__ counts,       // [B][NSEG]
                    int A) {
    __shared__ unsigned long long lin[SEG_CAP];   // 16 KB (scratch for picks first)
    __shared__ unsigned int plo[2][SEG_CAP];      // 16 KB
    __shared__ unsigned int phi[2][SEG_CAP];      // 16 KB
    __shared__ unsigned int ssum[256];
    __shared__ unsigned int pk[2];
    __shared__ unsigned int cnt;
    const int img = blockIdx.y;
    const int seg = blockIdx.x;
    const int tid = threadIdx.x;
    const int lane = tid & 63;
    const int w = tid >> 6;                       // wave 0..7
    const float* sc = scores + (size_t)img * A;

    // redundant pick1 + pick2 (scratch: reuse lin as a u32 cnt array)
    unsigned int* cnt32 = (unsigned int*)lin;
    pick_dev(ghist1 + (size_t)img * 2048, 21, 2048, 0u, (unsigned)PRE_N, cnt32, ssum, pk);
    const unsigned int p1 = pk[0];
    const unsigned int k1 = pk[1];
    pick_dev(ghist2 + (size_t)img * 2048, 10, 2048, p1, k1, cnt32, ssum, pk);
    const unsigned int T = pk[0];                 // 22-bit-prefix threshold

    if (tid == 0) cnt = 0u;
    for (int i = tid; i < SEG_CAP; i += 512) lin[i] = ~0ull;  // pad keys = max
    __syncthreads();

    // compact: groups g == seg (mod NSEG), wave-aggregated LDS push
    const int ngr = A >> 6;                       // 64-element groups (2304)
    const int nj = ngr / NSEG;                    // groups per segment (288)
    for (int j = w; j < nj; j += 8) {             // 36 iterations per wave
        int g = seg + j * NSEG;
        int i = (g << 6) + lane;
        unsigned int sv = __float_as_uint(sc[i]); // scores > 0: uint order == float order
        bool push = (sv >= T);
        unsigned long long bal = __ballot(push ? 1 : 0);
        if (push) {
            int leader = __ffsll(bal) - 1;
            int rank = __popcll(bal & ((1ull << lane) - 1ull));
            unsigned int base = 0;
            if (lane == leader) base = atomicAdd(&cnt, (unsigned int)__popcll(bal));
            base = (unsigned int)__shfl((int)base, leader);
            unsigned int pos = base + (unsigned int)rank;
            if (pos < SEG_CAP)
                lin[pos] = (((unsigned long long)(~sv)) << 32) | (unsigned long long)(unsigned int)i;
        }
    }
    __syncthreads();

    int n = (int)cnt; if (n > SEG_CAP) n = SEG_CAP;
    int P2 = 512; while (P2 < n) P2 <<= 1;        // 512..2048 (block-uniform)
    const int NT = P2 >> 3;                       // active threads
    const int t = tid;
    const bool act = (t < NT);

    unsigned long long v[8];
    if (act) {
        #pragma unroll
        for (int e = 0; e < 8; ++e) v[e] = lin[(t << 3) + e];
        // k=2,4,8 (in-register)
        CE(0,1,true) CE(2,3,false) CE(4,5,true) CE(6,7,false)
        CE(0,2,true) CE(1,3,true) CE(4,6,false) CE(5,7,false)
        CE(0,1,true) CE(2,3,true) CE(4,5,false) CE(6,7,false)
        bool u8 = ((t & 1) == 0);
        REG3(u8)
    }
    int b = 0;
    for (int k = 16; k <= P2; k <<= 1) {
        const bool up = (((t << 3) & k) == 0);
        for (int j = k >> 1; j >= 8; j >>= 1) {
            const int c = j >> 3;
            if (act) {
                #pragma unroll
                for (int e = 0; e < 8; ++e) {
                    int idx = e * NT + t;
                    plo[b][idx] = (unsigned int)v[e];
                    phi[b][idx] = (unsigned int)(v[e] >> 32);
                }
            }
            __syncthreads();
            if (act) {
                const int q = t ^ c;
                const bool keep_min = (up == ((t & c) == 0));
                #pragma unroll
                for (int e = 0; e < 8; ++e) {
                    int idx = e * NT + q;
                    unsigned long long wv = ((unsigned long long)phi[b][idx] << 32)
                                          | (unsigned long long)plo[b][idx];
                    bool less = v[e] < wv;
                    v[e] = (less == keep_min) ? v[e] : wv;
                }
            }
            b ^= 1;
        }
        if (act) { REG3(up) }
    }

    unsigned long long* gp = pool + ((size_t)img * NSEG + seg) * SEG_CAP;
    if (act) {
        #pragma unroll
        for (int e = 0; e < 8; ++e) {
            int r = (t << 3) + e;
            if (r < n) gp[r] = v[e];
        }
    }
    if (tid == 0) counts[img * NSEG + seg] = (unsigned int)n;
}

// ---------------- stage 2d: rank (merge by binary search) + decode ----------------
__global__ void __launch_bounds__(256)
rank_decode_kernel(const unsigned long long* __restrict__ pool,
                   const unsigned int* __restrict__ counts,
                   const float* __restrict__ deltas,   // [B][A][4]
                   const float* __restrict__ anchors,  // [A][4]
                   float* __restrict__ pre_boxes,      // [B][6000][4]
                   float* __restrict__ pre_scores,     // [B][6000]
                   int A) {
    __shared__ unsigned long long arr[RANK_LDS];   // 64 KB (total ~6000 -> fast path)
    const int img = blockIdx.y;
    const int seg = blockIdx.x;
    const int tid = threadIdx.x;

    int c[NSEG], off[NSEG + 1];
    const unsigned long long* gp[NSEG];
    off[0] = 0;
    #pragma unroll
    for (int s = 0; s < NSEG; ++s) {
        int cs = (int)counts[img * NSEG + s];
        if (cs > SEG_CAP) cs = SEG_CAP;
        c[s] = cs;
        off[s + 1] = off[s] + cs;
        gp[s] = pool + ((size_t)img * NSEG + s) * SEG_CAP;
    }
    const int total = off[NSEG];
    const bool inlds = (total <= RANK_LDS);
    if (inlds) {
        #pragma unroll
        for (int s = 0; s < NSEG; ++s)
            for (int i = tid; i < c[s]; i += 256) arr[off[s] + i] = gp[s][i];
    }
    __syncthreads();

    const int m = c[seg];
    for (int i = tid; i < m; i += 256) {
        unsigned long long key = inlds ? arr[off[seg] + i] : gp[seg][i];
        int pos = i;
        #pragma unroll
        for (int s = 0; s < NSEG; ++s) {
            if (s == seg) continue;
            const unsigned long long* base = inlds ? (arr + off[s]) : gp[s];
            int lo = 0, hi = c[s];
            while (lo < hi) {
                int mid = (lo + hi) >> 1;
                if (base[mid] < key) lo = mid + 1; else hi = mid;
            }
            pos += lo;
        }
        if (pos < PRE_N) {
            unsigned int bidx = (unsigned int)(key & 0xFFFFFFFFull);
            unsigned int sbits = ~((unsigned int)(key >> 32));
            float score = __uint_as_float(sbits);
            float a0 = anchors[(size_t)bidx * 4 + 0];
            float a1 = anchors[(size_t)bidx * 4 + 1];
            float a2 = anchors[(size_t)bidx * 4 + 2];
            float a3 = anchors[(size_t)bidx * 4 + 3];
            const float* dd = deltas + ((size_t)img * A + bidx) * 4;
            float d0 = dd[0] * 0.1f;
            float d1 = dd[1] * 0.1f;
            float d2 = dd[2] * 0.2f;
            float d3 = dd[3] * 0.2f;
            float anc_w = a3 - a1;
            float anc_h = a2 - a0;
            float anc_cx = a1 + 0.5f * anc_w;
            float anc_cy = a0 + 0.5f * anc_h;
            float bb_w = expf(d3) * anc_w;
            float bb_h = expf(d2) * anc_h;
            float bb_cx = d1 * anc_w + anc_cx;
            float bb_cy = d0 * anc_h + anc_cy;
            float y1 = bb_cy - 0.5f * bb_h;
            float x1 = bb_cx - 0.5f * bb_w;
            float y2 = bb_h + y1;
            float x2 = bb_w + x1;
            float* ob = pre_boxes + ((size_t)img * PRE_N + pos) * 4;
            ob[0] = y1; ob[1] = x1; ob[2] = y2; ob[3] = x2;
            pre_scores[(size_t)img * PRE_N + pos] = score;
        }
    }
}

// ---------------- stage 3: chunked greedy NMS (round-8 known-good, untouched) ----------------
__global__ void __launch_bounds__(NMS_BLOCK)
nms_kernel(const float* __restrict__ pre_boxes,
           const float* __restrict__ pre_scores,
           float* __restrict__ out_boxes,    // [B][300][4] (pre-zeroed)
           float* __restrict__ out_scores) { // [B][300]
    const int img = blockIdx.x;
    const int tid = threadIdx.x;
    const int lane = tid & 63;
    const int grp = tid >> 6;                 // 0..7
    const float4* bb4 = (const float4*)(pre_boxes + (size_t)img * PRE_N * 4);

    __shared__ float4 kept[POST_N];
    __shared__ float  kept_area[POST_N];
    __shared__ int    kept_idx[POST_N];
    __shared__ float4 chunkbox[2][64];              // double buffer
    __shared__ unsigned long long rows[64];         // row i: boxes suppressed by pivot i
    __shared__ unsigned long long supball[8];       // phase-E per-wave suppressed sets
    __shared__ int kept_cnt;

    const int NCH = (PRE_N + 63) >> 6;        // 94 (last chunk: 48 valid)

    // prologue: stage chunk 0, prefetch chunk 1, init
    float4 nb = make_float4(0.f, 0.f, 0.f, 0.f);
    if (tid < 64) {
        chunkbox[0][tid] = bb4[tid];
        nb = bb4[64 + tid];                   // chunk 1 fully valid (128 <= 6000)
    }
    if (tid == 0) kept_cnt = 0;
    __syncthreads();

    for (int c = 0; c < NCH; ++c) {
        const int base = c << 6;
        const int cur = c & 1;
        const int K = kept_cnt;
        float4 mb = chunkbox[cur][lane];
        float marea = (mb.z - mb.x) * (mb.w - mb.y);

        // ---- phase E: external suppression vs previously-kept boxes ----
        bool sup = false;
        for (int k = grp; k < K; k += 8) {
            float4 pb = kept[k];              // uniform LDS addr per wave -> broadcast
            float pa = kept_area[k];
            SUPP(pb, pa, mb, marea, s)
            if (s) { sup = true; break; }
        }
        unsigned long long bal = __ballot(sup ? 1 : 0);
        if (lane == 0) supball[grp] = bal;    // always write (0 when none)

        // ---- phase M: row masks (8 pivots per wave vs all 64 boxes) ----
        #pragma unroll
        for (int u = 0; u < 8; ++u) {
            const int i = (grp << 3) + u;
            float4 pb = chunkbox[cur][i];     // uniform per iteration -> broadcast
            float pa = (pb.z - pb.x) * (pb.w - pb.y);
            SUPP(pb, pa, mb, marea, s)
            unsigned long long rb = __ballot(s ? 1 : 0);
            if (lane == 0) rows[i] = rb;
        }

        // ---- staging: publish chunk c+1, prefetch chunk c+2 ----
        if (tid < 64) {
            chunkbox[cur ^ 1][tid] = nb;
            int j = base + 128 + tid;
            nb = (j < PRE_N) ? bb4[j] : make_float4(0.f, 0.f, 0.f, 0.f);
        }
        __syncthreads();                      // (B) supball + rows + staging visible

        // ---- phase R: wave-0 ffs-ordered resolution over alive boxes only ----
        if (grp == 0) {
            const int remn = PRE_N - base;
            unsigned long long ext = (remn >= 64) ? ~0ull : ((1ull << remn) - 1ull);
            unsigned long long sb = supball[0] | supball[1] | supball[2] | supball[3]
                                  | supball[4] | supball[5] | supball[6] | supball[7];
            unsigned long long rem = ext & ~sb;
            unsigned long long myrow = rows[lane];   // row for pivot 'lane'
            int kc = K;
            while (rem && kc < POST_N) {
                const int i = __ffsll(rem) - 1;      // lowest alive = highest score
                if (lane == i) {                     // lane i holds box i in registers
                    kept[kc] = mb;
                    kept_area[kc] = marea;
                    kept_idx[kc] = base + i;
                }
                unsigned long long ri = __shfl(myrow, i);
                rem &= ~(1ull << i);
                rem &= ~ri;                          // row's j<i bits unreachable (ffs)
                ++kc;
            }
            if (lane == 0) kept_cnt = kc;
        }
        __syncthreads();                      // (C) kept list + count visible
        if (kept_cnt >= POST_N) break;        // uniform
    }

    // ---- write outputs (rest of the pre-zeroed buffer stays zero) ----
    const int kc = kept_cnt;
    for (int r = tid; r < kc; r += NMS_BLOCK) {
        float4 bx = kept[r];
        float* ob = out_boxes + ((size_t)img * POST_N + r) * 4;
        ob[0] = bx.x; ob[1] = bx.y; ob[2] = bx.z; ob[3] = bx.w;
        out_scores[(size_t)img * POST_N + r] =
            pre_scores[(size_t)img * PRE_N + kept_idx[r]];
    }
}

extern "C" void kernel_launch(void* const* d_in, const int* in_sizes, int n_in,
                              void* d_out, int out_size, void* d_ws, size_t ws_size,
                              hipStream_t stream) {
    const float* deltas  = (const float*)d_in[0];  // (B, A, 4)
    const float* labels  = (const float*)d_in[1];  // (B, FH, FW, 9)
    const float* anchors = (const float*)d_in[2];  // (A, 4)
    float* out = (float*)d_out;

    const int A = in_sizes[2] / 4;                 // 147456
    const int B = in_sizes[0] / (A * 4);           // 32
    const int ngroups = in_sizes[1] / KCLS;        // B*FH*FW
    const int gpi = ngroups / B;                   // 16384

    // workspace layout
    float* scores     = (float*)d_ws;                                // B*A
    float* pre_boxes  = scores + (size_t)B * A;                      // B*6000*4
    float* pre_scores = pre_boxes + (size_t)B * PRE_N * 4;           // B*6000
    unsigned int* hist  = (unsigned int*)(pre_scores + (size_t)B * PRE_N);  // 2*B*2048
    unsigned long long* pool = (unsigned long long*)(hist + (size_t)2 * B * 2048); // B*NSEG*SEG_CAP
    unsigned int* counts = (unsigned int*)(pool + (size_t)B * NSEG * SEG_CAP);     // B*NSEG

    unsigned int* ghist1 = hist;
    unsigned int* ghist2 = hist + (size_t)B * 2048;

    float* out_boxes  = out;                        // B*300*4
    float* out_scores = out + (size_t)B * POST_N * 4;

    hipMemsetAsync(d_out, 0, (size_t)out_size * sizeof(float), stream);
    hipMemsetAsync(hist, 0, (size_t)2 * B * 2048 * sizeof(unsigned int), stream);

    // pass 1 (bits [31:21]) fused into softmax
    softmax_hist_kernel<<<ngroups / 256, 256, 0, stream>>>(labels, scores, ghist1, gpi);

    // pass 2 (bits [20:10]); pick1 computed redundantly in-block
    dim3 hgrid(CHUNKS_PER_IMG, B);
    hist2_kernel<<<hgrid, HIST_BLOCK, 0, stream>>>(scores, ghist1, ghist2, A);

    // compact+sort; pick1+pick2 computed redundantly in-block
    dim3 sgrid(NSEG, B);
    compact_sort_kernel<<<sgrid, 512, 0, stream>>>(scores, ghist1, ghist2, pool, counts, A);
    rank_decode_kernel<<<sgrid, 256, 0, stream>>>(pool, counts, deltas, anchors,
                                                  pre_boxes, pre_scores, A);

    nms_kernel<<<B, NMS_BLOCK, 0, stream>>>(pre_boxes, pre_scores, out_boxes, out_scores);
}

// Round 11
// 259.082 us; speedup vs baseline: 1.0204x; 1.0149x over previous
//
#include <hip/hip_runtime.h>
#include <cstdint>
#include <cstddef>

// Match numpy/XLA float32 semantics: no FMA contraction anywhere.
#pragma clang fp contract(off)

#define KCLS 9
#define PRE_N 6000
#define POST_N 300
#define NMS_IOU_T 0.7f
#define HIST_BLOCK 256
#define CHUNKS_PER_IMG 32
#define NMS_BLOCK 512
#define NSEG 8
#define SEG_CAP 2048
#define RANK_LDS 8192   // rank_decode fast-path capacity (total candidates ~6000+eps)

// Decisive-margin suppression test: multiply prescreen with +-1e-6 margins,
// exact reference division only in the borderline window -> bit-identical
// decisions to `inter/den > 0.7f` with reference float op order.
#define SUPP(pb, pa, mbx, mar, out) \
    bool out; { \
        float iy1_ = fmaxf((pb).x, (mbx).x); \
        float ix1_ = fmaxf((pb).y, (mbx).y); \
        float iy2_ = fminf((pb).z, (mbx).z); \
        float ix2_ = fminf((pb).w, (mbx).w); \
        float ih_ = iy2_ - iy1_; ih_ = ih_ > 0.f ? ih_ : 0.f; \
        float iw_ = ix2_ - ix1_; iw_ = iw_ > 0.f ? iw_ : 0.f; \
        float inter_ = ih_ * iw_; \
        float den_ = (mar) + (pa) - inter_ + 1e-9f; \
        float hi_ = 0.7000007f * den_; \
        float lo_ = 0.6999993f * den_; \
        out = inter_ > hi_; \
        if (inter_ >= lo_ && inter_ <= hi_) out = (inter_ / den_) > NMS_IOU_T; \
    }

// ---- in-block pick: suffix-scan a 2048-bin global histogram (L2-resident) ----
__device__ __forceinline__ void pick_dev(
        const unsigned int* __restrict__ gh,   // [bins] global histogram
        int shift, int bins,
        unsigned int prefix_in, unsigned int krem_in,
        unsigned int* cnt,      // LDS >= bins
        unsigned int* ssum,     // LDS 256
        unsigned int* out) {    // LDS 2
    const int t = threadIdx.x;
    const int per = bins >> 8;
    unsigned int my = 0;
    if (t < 256) {
        for (int i = 0; i < per; ++i) {
            unsigned int c = gh[t * per + i];
            cnt[t * per + i] = c;
            my += c;
        }
        ssum[t] = my;
    }
    __syncthreads();
    // inclusive suffix scan over the 256 chunk sums
    for (int d = 1; d < 256; d <<= 1) {
        unsigned int v = 0u;
        if (t < 256 && t + d < 256) v = ssum[t + d];
        __syncthreads();
        if (t < 256) ssum[t] += v;
        __syncthreads();
    }
    if (t < 256) {
        unsigned int above = ssum[t] - my;        // strictly above my chunk
        if (above < krem_in && ssum[t] >= krem_in) {   // unique thread
            unsigned int cum = above;
            for (int b = per - 1; b >= 0; --b) {
                unsigned int c = cnt[t * per + b];
                if (cum + c >= krem_in) {
                    out[0] = prefix_in | ((unsigned int)(t * per + b) << shift);
                    out[1] = krem_in - cum;
                    break;
                }
                cum += c;
            }
        }
    }
    __syncthreads();
}

// ---------------- stage 1: softmax over K=9 (coalesced IO) + pass-1 hist (sub x4) ----------------
__global__ void __launch_bounds__(256)
softmax_hist_kernel(const float* __restrict__ labels,
                    float* __restrict__ scores,
                    unsigned int* __restrict__ ghist,   // [B][2048] (pass-1 slot)
                    int gpi) {                          // groups per image (16384)
    __shared__ float buf[256 * KCLS];                   // 9216 B
    __shared__ unsigned int h[2048 * 4];                // 32 KB, 4 sub-histograms
    const int tid = threadIdx.x;
    for (int i = tid; i < 2048 * 4; i += 256) h[i] = 0u;

    const size_t gbase = (size_t)blockIdx.x * (256 * KCLS);
    const float4* lin4 = (const float4*)(labels + gbase);
    float4* b4 = (float4*)buf;
    for (int i = tid; i < 576; i += 256) b4[i] = lin4[i];   // coalesced 16B loads
    __syncthreads();

    // per-thread softmax on buf[tid*9 .. +8]; stride-9 LDS = 2-way aliasing (free)
    const int sub = tid & 3;                            // 4-way same-address spread
    float v[KCLS];
    float m = -1e30f;
    #pragma unroll
    for (int k = 0; k < KCLS; ++k) { v[k] = buf[tid * KCLS + k]; m = fmaxf(m, v[k]); }
    float e[KCLS];
    float s = 0.f;
    #pragma unroll
    for (int k = 0; k < KCLS; ++k) { e[k] = expf(v[k] - m); s += e[k]; }
    #pragma unroll
    for (int k = 0; k < KCLS; ++k) {
        float r = e[k] / s;
        buf[tid * KCLS + k] = r;                        // own slots only: no hazard
        atomicAdd(&h[(((__float_as_uint(r) >> 21) & 2047u) << 2) | sub], 1u);
    }
    __syncthreads();

    float4* o4 = (float4*)(scores + gbase);
    for (int i = tid; i < 576; i += 256) o4[i] = b4[i];     // coalesced 16B stores

    const int img0 = (blockIdx.x * 256) / gpi;          // block spans one image
    unsigned int* gh = ghist + (size_t)img0 * 2048;
    for (int i = tid; i < 2048; i += 256) {
        unsigned int c = h[4 * i] + h[4 * i + 1] + h[4 * i + 2] + h[4 * i + 3];
        if (c) atomicAdd(&gh[i], c);
    }
}

// ---------------- stage 2a: radix pass 2 (in-block pick1 + histogram) ----------------
__global__ void __launch_bounds__(HIST_BLOCK)
hist2_kernel(const float* __restrict__ scores,
             const unsigned int* __restrict__ ghist1,   // [B][2048] pass-1
             unsigned int* __restrict__ ghist2,         // [B][2048] pass-2
             int A) {
    __shared__ unsigned int h[2048];
    __shared__ unsigned int ssum[256];
    __shared__ unsigned int pk[2];
    const int img = blockIdx.y;
    const int chunk = blockIdx.x;
    const int tid = threadIdx.x;

    // redundant pick1: bins [31:21], krem = 6000
    pick_dev(ghist1 + (size_t)img * 2048, 21, 2048, 0u, (unsigned)PRE_N, h, ssum, pk);
    const unsigned int prefix = pk[0];                  // low 21 bits zero

    for (int i = tid; i < 2048; i += HIST_BLOCK) h[i] = 0u;
    __syncthreads();
    const int per = A / CHUNKS_PER_IMG;
    const float* sc = scores + (size_t)img * A + (size_t)chunk * per;
    for (int i = tid; i < per; i += HIST_BLOCK) {
        unsigned int v = __float_as_uint(sc[i]);   // scores > 0: uint order == float order
        if ((v & 0xFFE00000u) == prefix)
            atomicAdd(&h[(v >> 10) & 2047u], 1u);
    }
    __syncthreads();
    unsigned int* gh = ghist2 + (size_t)img * 2048;
    for (int i = tid; i < 2048; i += HIST_BLOCK) {
        unsigned int c = h[i];
        if (c) atomicAdd(&gh[i], c);
    }
}

// ---------------- stage 2c: per-segment compact + register-blocked bitonic sort ----------------
// In-block pick1+pick2 -> T = top-22-bit prefix of the 6000th-largest score
// (low 10 bits zero). Loose-but-safe threshold; exact top-6000 cut happens on
// full 64-bit keys in rank_decode -> output identical.
#define CE(a, b, u) { if ((v[a] > v[b]) == (u)) { unsigned long long t_ = v[a]; v[a] = v[b]; v[b] = t_; } }
#define REG3(u) { CE(0,4,u) CE(1,5,u) CE(2,6,u) CE(3,7,u) \
                  CE(0,2,u) CE(1,3,u) CE(4,6,u) CE(5,7,u) \
                  CE(0,1,u) CE(2,3,u) CE(4,5,u) CE(6,7,u) }

__global__ void __launch_bounds__(512)
compact_sort_kernel(const float* __restrict__ scores,
                    const unsigned int* __restrict__ ghist1,
                    const unsigned int* __restrict__ ghist2,
                    unsigned long long* __restrict__ pool,   // [B][NSEG][SEG_CAP]
                    unsigned int* __restrict__ counts,       // [B][NSEG]
                    int A) {
    __shared__ unsigned long long lin[SEG_CAP];   // 16 KB (scratch for picks first)
    __shared__ unsigned int plo[2][SEG_CAP];      // 16 KB
    __shared__ unsigned int phi[2][SEG_CAP];      // 16 KB
    __shared__ unsigned int ssum[256];
    __shared__ unsigned int pk[2];
    __shared__ unsigned int cnt;
    const int img = blockIdx.y;
    const int seg = blockIdx.x;
    const int tid = threadIdx.x;
    const int lane = tid & 63;
    const int w = tid >> 6;                       // wave 0..7
    const float* sc = scores + (size_t)img * A;

    // redundant pick1 + pick2 (scratch: reuse lin as a u32 cnt array)
    unsigned int* cnt32 = (unsigned int*)lin;
    pick_dev(ghist1 + (size_t)img * 2048, 21, 2048, 0u, (unsigned)PRE_N, cnt32, ssum, pk);
    const unsigned int p1 = pk[0];
    const unsigned int k1 = pk[1];
    pick_dev(ghist2 + (size_t)img * 2048, 10, 2048, p1, k1, cnt32, ssum, pk);
    const unsigned int T = pk[0];                 // 22-bit-prefix threshold

    if (tid == 0) cnt = 0u;
    for (int i = tid; i < SEG_CAP; i += 512) lin[i] = ~0ull;  // pad keys = max
    __syncthreads();

    // compact: groups g == seg (mod NSEG), wave-aggregated LDS push
    const int ngr = A >> 6;                       // 64-element groups (2304)
    const int nj = ngr / NSEG;                    // groups per segment (288)
    for (int j = w; j < nj; j += 8) {             // 36 iterations per wave
        int g = seg + j * NSEG;
        int i = (g << 6) + lane;
        unsigned int sv = __float_as_uint(sc[i]); // scores > 0: uint order == float order
        bool push = (sv >= T);
        unsigned long long bal = __ballot(push ? 1 : 0);
        if (push) {
            int leader = __ffsll(bal) - 1;
            int rank = __popcll(bal & ((1ull << lane) - 1ull));
            unsigned int base = 0;
            if (lane == leader) base = atomicAdd(&cnt, (unsigned int)__popcll(bal));
            base = (unsigned int)__shfl((int)base, leader);
            unsigned int pos = base + (unsigned int)rank;
            if (pos < SEG_CAP)
                lin[pos] = (((unsigned long long)(~sv)) << 32) | (unsigned long long)(unsigned int)i;
        }
    }
    __syncthreads();

    int n = (int)cnt; if (n > SEG_CAP) n = SEG_CAP;
    int P2 = 512; while (P2 < n) P2 <<= 1;        // 512..2048 (block-uniform)
    const int NT = P2 >> 3;                       // active threads
    const int t = tid;
    const bool act = (t < NT);

    unsigned long long v[8];
    if (act) {
        #pragma unroll
        for (int e = 0; e < 8; ++e) v[e] = lin[(t << 3) + e];
        // k=2,4,8 (in-register)
        CE(0,1,true) CE(2,3,false) CE(4,5,true) CE(6,7,false)
        CE(0,2,true) CE(1,3,true) CE(4,6,false) CE(5,7,false)
        CE(0,1,true) CE(2,3,true) CE(4,5,false) CE(6,7,false)
        bool u8 = ((t & 1) == 0);
        REG3(u8)
    }
    int b = 0;
    for (int k = 16; k <= P2; k <<= 1) {
        const bool up = (((t << 3) & k) == 0);
        for (int j = k >> 1; j >= 8; j >>= 1) {
            const int c = j >> 3;
            if (act) {
                #pragma unroll
                for (int e = 0; e < 8; ++e) {
                    int idx = e * NT + t;
                    plo[b][idx] = (unsigned int)v[e];
                    phi[b][idx] = (unsigned int)(v[e] >> 32);
                }
            }
            __syncthreads();
            if (act) {
                const int q = t ^ c;
                const bool keep_min = (up == ((t & c) == 0));
                #pragma unroll
                for (int e = 0; e < 8; ++e) {
                    int idx = e * NT + q;
                    unsigned long long wv = ((unsigned long long)phi[b][idx] << 32)
                                          | (unsigned long long)plo[b][idx];
                    bool less = v[e] < wv;
                    v[e] = (less == keep_min) ? v[e] : wv;
                }
            }
            b ^= 1;
        }
        if (act) { REG3(up) }
    }

    unsigned long long* gp = pool + ((size_t)img * NSEG + seg) * SEG_CAP;
    if (act) {
        #pragma unroll
        for (int e = 0; e < 8; ++e) {
            int r = (t << 3) + e;
            if (r < n) gp[r] = v[e];
        }
    }
    if (tid == 0) counts[img * NSEG + seg] = (unsigned int)n;
}

// ---------------- stage 2d: rank (merge by binary search) + decode ----------------
__global__ void __launch_bounds__(256)
rank_decode_kernel(const unsigned long long* __restrict__ pool,
                   const unsigned int* __restrict__ counts,
                   const float* __restrict__ deltas,   // [B][A][4]
                   const float* __restrict__ anchors,  // [A][4]
                   float* __restrict__ pre_boxes,      // [B][6000][4]
                   float* __restrict__ pre_scores,     // [B][6000]
                   int A) {
    __shared__ unsigned long long arr[RANK_LDS];   // 64 KB (total ~6000 -> fast path)
    const int img = blockIdx.y;
    const int seg = blockIdx.x;
    const int tid = threadIdx.x;

    int c[NSEG], off[NSEG + 1];
    const unsigned long long* gp[NSEG];
    off[0] = 0;
    #pragma unroll
    for (int s = 0; s < NSEG; ++s) {
        int cs = (int)counts[img * NSEG + s];
        if (cs > SEG_CAP) cs = SEG_CAP;
        c[s] = cs;
        off[s + 1] = off[s] + cs;
        gp[s] = pool + ((size_t)img * NSEG + s) * SEG_CAP;
    }
    const int total = off[NSEG];
    const bool inlds = (total <= RANK_LDS);
    if (inlds) {
        #pragma unroll
        for (int s = 0; s < NSEG; ++s)
            for (int i = tid; i < c[s]; i += 256) arr[off[s] + i] = gp[s][i];
    }
    __syncthreads();

    const int m = c[seg];
    for (int i = tid; i < m; i += 256) {
        unsigned long long key = inlds ? arr[off[seg] + i] : gp[seg][i];
        int pos = i;
        #pragma unroll
        for (int s = 0; s < NSEG; ++s) {
            if (s == seg) continue;
            const unsigned long long* base = inlds ? (arr + off[s]) : gp[s];
            int lo = 0, hi = c[s];
            while (lo < hi) {
                int mid = (lo + hi) >> 1;
                if (base[mid] < key) lo = mid + 1; else hi = mid;
            }
            pos += lo;
        }
        if (pos < PRE_N) {
            unsigned int bidx = (unsigned int)(key & 0xFFFFFFFFull);
            unsigned int sbits = ~((unsigned int)(key >> 32));
            float score = __uint_as_float(sbits);
            float a0 = anchors[(size_t)bidx * 4 + 0];
            float a1 = anchors[(size_t)bidx * 4 + 1];
            float a2 = anchors[(size_t)bidx * 4 + 2];
            float a3 = anchors[(size_t)bidx * 4 + 3];
            const float* dd = deltas + ((size_t)img * A + bidx) * 4;
            float d0 = dd[0] * 0.1f;
            float d1 = dd[1] * 0.1f;
            float d2 = dd[2] * 0.2f;
            float d3 = dd[3] * 0.2f;
            float anc_w = a3 - a1;
            float anc_h = a2 - a0;
            float anc_cx = a1 + 0.5f * anc_w;
            float anc_cy = a0 + 0.5f * anc_h;
            float bb_w = expf(d3) * anc_w;
            float bb_h = expf(d2) * anc_h;
            float bb_cx = d1 * anc_w + anc_cx;
            float bb_cy = d0 * anc_h + anc_cy;
            float y1 = bb_cy - 0.5f * bb_h;
            float x1 = bb_cx - 0.5f * bb_w;
            float y2 = bb_h + y1;
            float x2 = bb_w + x1;
            float* ob = pre_boxes + ((size_t)img * PRE_N + pos) * 4;
            ob[0] = y1; ob[1] = x1; ob[2] = y2; ob[3] = x2;
            pre_scores[(size_t)img * PRE_N + pos] = score;
        }
    }
}

// ---------------- stage 3: chunked greedy NMS (pipelined: R(c) overlaps M(c+1)) ----------------
// Round-8/10 structure with the within-chunk matrix M moved OFF the critical
// path: while wave 0 resolves chunk c (phase R, using rows[cur] precomputed
// last iteration), waves 1-7 compute chunk c+1's row-matrix into rows[cur^1]
// (pivots i = (grp-1)+7u), and wave 1 publishes chunk c+2 / prefetches c+3.
// Chunk 0's matrix is computed in the prologue. Decisions identical: same E,
// same row contents, same ffs-ordered resolution.
// Buffer audit: R reads no chunkbox; publish target chunkbox[cur] is dead
// after E (WAR separated by barrier B, next read >= 2 barriers later); M'
// reads only chunkbox[cur^1]; rows buffers disjoint.
__global__ void __launch_bounds__(NMS_BLOCK)
nms_kernel(const float* __restrict__ pre_boxes,
           const float* __restrict__ pre_scores,
           float* __restrict__ out_boxes,    // [B][300][4] (pre-zeroed)
           float* __restrict__ out_scores) { // [B][300]
    const int img = blockIdx.x;
    const int tid = threadIdx.x;
    const int lane = tid & 63;
    const int grp = tid >> 6;                 // 0..7
    const float4* bb4 = (const float4*)(pre_boxes + (size_t)img * PRE_N * 4);

    __shared__ float4 kept[POST_N];
    __shared__ float  kept_area[POST_N];
    __shared__ int    kept_idx[POST_N];
    __shared__ float4 chunkbox[2][64];              // double buffer
    __shared__ unsigned long long rows[2][64];      // double-buffered row masks
    __shared__ unsigned long long supball[8];       // phase-E per-wave suppressed sets
    __shared__ int kept_cnt;

    const int NCH = (PRE_N + 63) >> 6;        // 94 (last chunk: 48 valid)

    // prologue: stage chunks 0,1; wave-1 register-prefetch chunk 2; M for chunk 0
    float4 nb = make_float4(0.f, 0.f, 0.f, 0.f);
    if (tid < 64) {
        chunkbox[0][tid] = bb4[tid];
        chunkbox[1][tid] = bb4[64 + tid];     // chunks 0,1 fully valid (128 <= 6000)
    }
    if (grp == 1) nb = bb4[128 + lane];       // chunk 2 fully valid (192 <= 6000)
    if (tid == 0) kept_cnt = 0;
    __syncthreads();
    {   // matrix for chunk 0 (all 8 waves, 8 pivots each) -> rows[0]
        float4 mb0 = chunkbox[0][lane];
        float mar0 = (mb0.z - mb0.x) * (mb0.w - mb0.y);
        #pragma unroll
        for (int u = 0; u < 8; ++u) {
            const int i = (grp << 3) + u;
            float4 pb = chunkbox[0][i];       // uniform per iteration -> broadcast
            float pa = (pb.z - pb.x) * (pb.w - pb.y);
            SUPP(pb, pa, mb0, mar0, s)
            unsigned long long rb = __ballot(s ? 1 : 0);
            if (lane == 0) rows[0][i] = rb;
        }
    }
    __syncthreads();

    for (int c = 0; c < NCH; ++c) {
        const int base = c << 6;
        const int cur = c & 1;
        const int K = kept_cnt;
        float4 mb = chunkbox[cur][lane];
        float marea = (mb.z - mb.x) * (mb.w - mb.y);

        // ---- phase E: external suppression vs previously-kept boxes ----
        bool sup = false;
        for (int k = grp; k < K; k += 8) {
            float4 pb = kept[k];              // uniform LDS addr per wave -> broadcast
            float pa = kept_area[k];
            SUPP(pb, pa, mb, marea, s)
            if (s) { sup = true; break; }
        }
        unsigned long long bal = __ballot(sup ? 1 : 0);
        if (lane == 0) supball[grp] = bal;    // always write (0 when none)
        __syncthreads();                      // (B) supball visible; chunkbox[cur] dead

        if (grp == 0) {
            // ---- phase R: ffs-ordered resolution over alive boxes only ----
            const int remn = PRE_N - base;
            unsigned long long ext = (remn >= 64) ? ~0ull : ((1ull << remn) - 1ull);
            unsigned long long sb = supball[0] | supball[1] | supball[2] | supball[3]
                                  | supball[4] | supball[5] | supball[6] | supball[7];
            unsigned long long rem = ext & ~sb;
            unsigned long long myrow = rows[cur][lane];   // row for pivot 'lane'
            int kc = K;
            while (rem && kc < POST_N) {
                const int i = __ffsll(rem) - 1;      // lowest alive = highest score
                if (lane == i) {                     // lane i holds box i in registers
                    kept[kc] = mb;
                    kept_area[kc] = marea;
                    kept_idx[kc] = base + i;
                }
                unsigned long long ri = __shfl(myrow, i);
                rem &= ~(1ull << i);
                rem &= ~ri;                          // row's j<i bits unreachable (ffs)
                ++kc;
            }
            if (lane == 0) kept_cnt = kc;
        } else if (c + 1 < NCH) {
            // ---- M' for chunk c+1 (waves 1-7, pivots i = (grp-1)+7u) ----
            float4 mb2 = chunkbox[cur ^ 1][lane];
            float mar2 = (mb2.z - mb2.x) * (mb2.w - mb2.y);
            for (int i = grp - 1; i < 64; i += 7) {
                float4 pb = chunkbox[cur ^ 1][i];    // uniform per iteration
                float pa = (pb.z - pb.x) * (pb.w - pb.y);
                SUPP(pb, pa, mb2, mar2, s)
                unsigned long long rb = __ballot(s ? 1 : 0);
                if (lane == 0) rows[cur ^ 1][i] = rb;
            }
            // staging (wave 1): publish chunk c+2 into the dead buffer, prefetch c+3
            if (grp == 1 && c + 2 < NCH) {
                chunkbox[cur][lane] = nb;
                int j = base + 192 + lane;           // chunk c+3
                nb = (j < PRE_N) ? bb4[j] : make_float4(0.f, 0.f, 0.f, 0.f);
            }
        }
        __syncthreads();                      // (C) kept list + rows[cur^1] + staging
        if (kept_cnt >= POST_N) break;        // uniform
    }

    // ---- write outputs (rest of the pre-zeroed buffer stays zero) ----
    const int kc = kept_cnt;
    for (int r = tid; r < kc; r += NMS_BLOCK) {
        float4 bx = kept[r];
        float* ob = out_boxes + ((size_t)img * POST_N + r) * 4;
        ob[0] = bx.x; ob[1] = bx.y; ob[2] = bx.z; ob[3] = bx.w;
        out_scores[(size_t)img * POST_N + r] =
            pre_scores[(size_t)img * PRE_N + kept_idx[r]];
    }
}

extern "C" void kernel_launch(void* const* d_in, const int* in_sizes, int n_in,
                              void* d_out, int out_size, void* d_ws, size_t ws_size,
                              hipStream_t stream) {
    const float* deltas  = (const float*)d_in[0];  // (B, A, 4)
    const float* labels  = (const float*)d_in[1];  // (B, FH, FW, 9)
    const float* anchors = (const float*)d_in[2];  // (A, 4)
    float* out = (float*)d_out;

    const int A = in_sizes[2] / 4;                 // 147456
    const int B = in_sizes[0] / (A * 4);           // 32
    const int ngroups = in_sizes[1] / KCLS;        // B*FH*FW
    const int gpi = ngroups / B;                   // 16384

    // workspace layout
    float* scores     = (float*)d_ws;                                // B*A
    float* pre_boxes  = scores + (size_t)B * A;                      // B*6000*4
    float* pre_scores = pre_boxes + (size_t)B * PRE_N * 4;           // B*6000
    unsigned int* hist  = (unsigned int*)(pre_scores + (size_t)B * PRE_N);  // 2*B*2048
    unsigned long long* pool = (unsigned long long*)(hist + (size_t)2 * B * 2048); // B*NSEG*SEG_CAP
    unsigned int* counts = (unsigned int*)(pool + (size_t)B * NSEG * SEG_CAP);     // B*NSEG

    unsigned int* ghist1 = hist;
    unsigned int* ghist2 = hist + (size_t)B * 2048;

    float* out_boxes  = out;                        // B*300*4
    float* out_scores = out + (size_t)B * POST_N * 4;

    hipMemsetAsync(d_out, 0, (size_t)out_size * sizeof(float), stream);
    hipMemsetAsync(hist, 0, (size_t)2 * B * 2048 * sizeof(unsigned int), stream);

    // pass 1 (bits [31:21]) fused into softmax
    softmax_hist_kernel<<<ngroups / 256, 256, 0, stream>>>(labels, scores, ghist1, gpi);

    // pass 2 (bits [20:10]); pick1 computed redundantly in-block
    dim3 hgrid(CHUNKS_PER_IMG, B);
    hist2_kernel<<<hgrid, HIST_BLOCK, 0, stream>>>(scores, ghist1, ghist2, A);

    // compact+sort; pick1+pick2 computed redundantly in-block
    dim3 sgrid(NSEG, B);
    compact_sort_kernel<<<sgrid, 512, 0, stream>>>(scores, ghist1, ghist2, pool, counts, A);
    rank_decode_kernel<<<sgrid, 256, 0, stream>>>(pool, counts, deltas, anchors,
                                                  pre_boxes, pre_scores, A);

    nms_kernel<<<B, NMS_BLOCK, 0, stream>>>(pre_boxes, pre_scores, out_boxes, out_scores);
}